// Round 4
// baseline (514.141 us; speedup 1.0000x reference)
//
#include <hip/hip_runtime.h>
#include <stdint.h>

#define B_ 16
#define T_ 4096
#define C_ 64
#define H_ 128
#define BQ 128
#define BK 64
#define KLS 136   // K LDS row stride in f16 (272 B, 16B-aligned rows, 4-bank row shift)
#define VS  72    // proj vt-transpose scratch stride (144 B rows, 16B-aligned)

typedef _Float16 f16;
typedef __attribute__((ext_vector_type(8))) _Float16 half8;   // 4 VGPRs (16x16x32 A/B)
typedef __attribute__((ext_vector_type(4))) _Float16 half4;   // 2 VGPRs (16x16x16 A/B)
typedef __attribute__((ext_vector_type(4))) float   floatx4;  // MFMA C/D frag

__device__ __forceinline__ f16 f2h(float f) { return (f16)f; }

__device__ __forceinline__ float fexp2(float x) {
#if __has_builtin(__builtin_amdgcn_exp2f)
    return __builtin_amdgcn_exp2f(x);
#else
    return exp2f(x);
#endif
}

// async global->LDS, 16 B per lane, dest = wave-uniform base + lane*16
__device__ __forceinline__ void async_cp16(const void* g, void* l) {
    __builtin_amdgcn_global_load_lds(
        (const __attribute__((address_space(1))) unsigned int*)g,
        (__attribute__((address_space(3))) unsigned int*)l, 16, 0, 0);
}

// ---------------------------------------------------------------------------
// Projections: q,k -> f16 [B][T][H]; v -> f16 vt[B][H][T] (transposed)
// fp32 VALU compute; f16 output (11-bit mantissa > bf16's 8).
// ---------------------------------------------------------------------------
__global__ __launch_bounds__(256) void proj_kernel(
    const float* __restrict__ x, const float* __restrict__ Wk,
    const float* __restrict__ Wq, const float* __restrict__ Wv,
    f16* __restrict__ qo, f16* __restrict__ ko, f16* __restrict__ vto)
{
    __shared__ __align__(16) char smem[48 * 1024];
    float* xl = (float*)smem;                       // [64][64] fp32 x tile
    float* wl = (float*)(smem + 16384);             // [64][128] fp32 W
    f16* vtl  = (f16*)(smem + 16384);               // [128][VS] f16 (aliases wl)

    const int tid = threadIdx.x;
    const int b   = blockIdx.x >> 6;
    const int t0  = (blockIdx.x & 63) * 64;

    #pragma unroll
    for (int it = 0; it < 4; ++it) {
        int r = (tid >> 4) + it * 16;
        int c = (tid & 15) * 4;
        *(float4*)&xl[r * 64 + c] =
            *(const float4*)(x + ((size_t)(b * T_ + t0 + r)) * C_ + c);
    }

    const int h0 = (tid & 31) * 4;
    const int rg = tid >> 5;

    for (int m = 0; m < 3; ++m) {
        const float* W = (m == 0) ? Wk : (m == 1) ? Wq : Wv;
        __syncthreads();
        #pragma unroll
        for (int it = 0; it < 8; ++it) {
            int r = (tid >> 5) + it * 8;
            int c = (tid & 31) * 4;
            *(float4*)&wl[r * 128 + c] = *(const float4*)(W + r * 128 + c);
        }
        __syncthreads();

        float acc[8][4];
        #pragma unroll
        for (int i = 0; i < 8; ++i)
            #pragma unroll
            for (int j = 0; j < 4; ++j) acc[i][j] = 0.f;

        #pragma unroll 8
        for (int c = 0; c < 64; ++c) {
            float4 w = *(const float4*)&wl[c * 128 + h0];
            #pragma unroll
            for (int i = 0; i < 8; ++i) {
                float xi = xl[(rg * 8 + i) * 64 + c];
                acc[i][0] += xi * w.x;
                acc[i][1] += xi * w.y;
                acc[i][2] += xi * w.z;
                acc[i][3] += xi * w.w;
            }
        }

        if (m < 2) {
            f16* o = (m == 0) ? ko : qo;
            #pragma unroll
            for (int i = 0; i < 8; ++i) {
                half4 pk = {f2h(acc[i][0]), f2h(acc[i][1]), f2h(acc[i][2]), f2h(acc[i][3])};
                *(half4*)(o + ((size_t)(b * T_ + t0 + rg * 8 + i)) * H_ + h0) = pk;
            }
        } else {
            __syncthreads();
            #pragma unroll
            for (int i = 0; i < 8; ++i)
                #pragma unroll
                for (int c2 = 0; c2 < 4; ++c2)
                    vtl[(h0 + c2) * VS + rg * 8 + i] = f2h(acc[i][c2]);
            __syncthreads();
            int h  = tid >> 1;
            int sg = (tid & 1) * 32;
            int4* dst = (int4*)(vto + ((size_t)(b * H_ + h)) * T_ + t0 + sg);
            const int4* src = (const int4*)&vtl[h * VS + sg];
            dst[0] = src[0]; dst[1] = src[1]; dst[2] = src[2]; dst[3] = src[3];
        }
    }
}

// ---------------------------------------------------------------------------
// Flash attention, chained-MFMA layout. Block = 4 waves, BQ=128, BK=64.
// St = K·Q^T via 16x16x32_f16 -> C-layout (lane: s=quad*4+r, q=col).
// exp2 -> half4 == EXACTLY the B-operand of mfma_f32_16x16x16f16
// (B[n=lane&15][k=quad*4+j]) -> PV chained with ZERO P data movement:
// Ot[h][q] += Vt-frag(A) · P-frag(B). Vt async-double-buffered in LDS
// (XOR-16B-granule swizzle); K prefetched to VGPRs after QK.
// s-split over blockIdx.z; combine_kernel merges/normalizes.
// ---------------------------------------------------------------------------
__global__ __launch_bounds__(256, 3) void attn_kernel(
    const f16* __restrict__ q,
    const f16* __restrict__ k,
    const f16* __restrict__ vt,
    float* __restrict__ O0, float* __restrict__ O1,
    float* __restrict__ Ls, int nsplit)
{
    __shared__ __align__(16) f16 Kl[64 * KLS];      // 17408 B
    __shared__ __align__(16) f16 Vtl[2][128 * 64];  // 32768 B (swizzled granules)

    const int tid  = threadIdx.x;
    const int wave = tid >> 6;
    const int lane = tid & 63;
    const int col  = lane & 15;
    const int quad = lane >> 4;
    const int qh   = quad >> 1;        // V-read granule16 select
    const int ql   = (quad & 1) * 4;   // V-read half-of-granule (f16 elems)
    const int b    = blockIdx.y;
    const int q0   = blockIdx.x * BQ;
    const int split  = blockIdx.z;
    const int NC     = T_ / BK / nsplit;
    const int s_base = split * (T_ / nsplit);

    const int krow = tid >> 4;          // K staging row (+16*it)
    const int kcol = (tid & 15) * 8;    // K staging col (f16)
    const int vrow = lane >> 3;         // Vt staging: row-in-call 0..7
    const int vswz = (lane & 7) ^ vrow; // Vt staging: swizzled source granule

    // Q fragments (reused NC chunks) — B-operand layout [n=lane&15][k=quad*8+j]
    half8 qf[2][4];
    #pragma unroll
    for (int qt = 0; qt < 2; ++qt) {
        const f16* qrow =
            q + ((size_t)(b * T_ + q0 + wave * 32 + qt * 16 + col)) * H_ + quad * 8;
        #pragma unroll
        for (int ks = 0; ks < 4; ++ks)
            qf[qt][ks] = *(const half8*)(qrow + ks * 32);
    }

    floatx4 o[2][8];   // Ot accum: o[qt][ht], lane: q=qt*16+col, h=ht*16+quad*4+r
    #pragma unroll
    for (int qt = 0; qt < 2; ++qt)
        #pragma unroll
        for (int ht = 0; ht < 8; ++ht) { o[qt][ht][0]=0.f; o[qt][ht][1]=0.f; o[qt][ht][2]=0.f; o[qt][ht][3]=0.f; }
    float lsum[2] = {0.f, 0.f};

    const float SC = 0.125f * 1.44269504088896340736f;  // scale * log2(e)

    int4 kr[4];
    #define LOAD_KR(S0)                                                           \
        do { _Pragma("unroll")                                                    \
            for (int it = 0; it < 4; ++it)                                        \
                kr[it] = *(const int4*)(k + ((size_t)(b * T_ + (S0) + krow + it * 16)) * H_ + kcol); \
        } while (0)

    #define ISSUE_VT(S0, BUF)                                                     \
        do { _Pragma("unroll")                                                    \
            for (int it = 0; it < 4; ++it) {                                      \
                int hbase = wave * 32 + it * 8;                                   \
                async_cp16(vt + ((size_t)(b * H_ + hbase + vrow)) * T_ + (S0) + vswz * 8, \
                           (void*)&Vtl[BUF][hbase * 64]);                         \
            }                                                                     \
        } while (0)

    LOAD_KR(s_base);
    ISSUE_VT(s_base, 0);

    for (int ci = 0; ci < NC; ++ci) {
        const int buf = ci & 1;
        // stage K chunk from prefetch regs (barrier drain also lands Vt(ci))
        #pragma unroll
        for (int it = 0; it < 4; ++it)
            *(int4*)&Kl[(krow + it * 16) * KLS + kcol] = kr[it];
        __syncthreads();                       // α: K + Vt(ci) visible
        if (ci + 1 < NC) ISSUE_VT(s_base + (ci + 1) * BK, buf ^ 1);

        // St = K·Q^T : rows=s (4 st-tiles), cols=q (2 qt-tiles), K-dim=128
        floatx4 s[2][4];
        #pragma unroll
        for (int qt = 0; qt < 2; ++qt)
            #pragma unroll
            for (int st = 0; st < 4; ++st) { s[qt][st][0]=0.f; s[qt][st][1]=0.f; s[qt][st][2]=0.f; s[qt][st][3]=0.f; }
        #pragma unroll
        for (int ks = 0; ks < 4; ++ks) {
            #pragma unroll
            for (int st = 0; st < 4; ++st) {
                half8 kf = *(const half8*)&Kl[(st * 16 + col) * KLS + ks * 32 + quad * 8];
                s[0][st] = __builtin_amdgcn_mfma_f32_16x16x32_f16(kf, qf[0][ks], s[0][st], 0, 0, 0);
                s[1][st] = __builtin_amdgcn_mfma_f32_16x16x32_f16(kf, qf[1][ks], s[1][st], 0, 0, 0);
            }
        }
        if (ci + 1 < NC) LOAD_KR(s_base + (ci + 1) * BK);   // prefetch next K

        // P = exp2(St*SC): C-layout regs ARE the 16x16x16 B-operand. No LDS.
        half4 pf[2][4];
        #pragma unroll
        for (int qt = 0; qt < 2; ++qt)
            #pragma unroll
            for (int st = 0; st < 4; ++st) {
                float p0 = fexp2(s[qt][st][0] * SC);
                float p1 = fexp2(s[qt][st][1] * SC);
                float p2 = fexp2(s[qt][st][2] * SC);
                float p3 = fexp2(s[qt][st][3] * SC);
                lsum[qt] += (p0 + p1) + (p2 + p3);
                pf[qt][st] = half4{f2h(p0), f2h(p1), f2h(p2), f2h(p3)};
            }

        // Ot += Vt·P : A = Vt[h=lane&15-tile][s=quad*4+j] (ds_read_b64, swizzled),
        // B = pf (in regs). 4 s-steps of 16 × 8 h-tiles × 2 q-tiles.
        #pragma unroll
        for (int sp = 0; sp < 4; ++sp) {
            const int sw = ((((sp * 2 + qh) ^ (col & 7)) << 3) + ql) + col * 64;
            #pragma unroll
            for (int ht = 0; ht < 8; ++ht) {
                half4 va = *(const half4*)&Vtl[buf][ht * 1024 + sw];
                o[0][ht] = __builtin_amdgcn_mfma_f32_16x16x16f16(va, pf[0][sp], o[0][ht], 0, 0, 0);
                o[1][ht] = __builtin_amdgcn_mfma_f32_16x16x16f16(va, pf[1][sp], o[1][ht], 0, 0, 0);
            }
        }
        __syncthreads();                       // β: Kl/Vtl[buf] reads done
    }
    #undef LOAD_KR
    #undef ISSUE_VT

    // epilogue: lane holds O[q=qt*16+col][h=ht*16+quad*4+r] (unnormalized)
    float* Op = (split == 0) ? O0 : O1;
    #pragma unroll
    for (int qt = 0; qt < 2; ++qt) {
        float l = lsum[qt];
        l += __shfl_xor(l, 16);
        l += __shfl_xor(l, 32);
        int qrow = q0 + wave * 32 + qt * 16 + col;
        if (quad == 0)
            Ls[(size_t)split * (B_ * T_) + b * T_ + qrow] = l;
        float* orow = Op + ((size_t)(b * T_ + qrow)) * H_;
        #pragma unroll
        for (int ht = 0; ht < 8; ++ht) {
            float4 st4 = {o[qt][ht][0], o[qt][ht][1], o[qt][ht][2], o[qt][ht][3]};
            *(float4*)&orow[ht * 16 + quad * 4] = st4;
        }
    }
}

// ---------------------------------------------------------------------------
// Merge s-split partials and normalize: out = (O0 [+ O1]) / (l0 [+ l1])
// ---------------------------------------------------------------------------
__global__ __launch_bounds__(256) void combine_kernel(
    float* __restrict__ out, const float* __restrict__ O1,
    const float* __restrict__ Ls, int nsplit)
{
    int i = blockIdx.x * 256 + threadIdx.x;   // float4 index, H/4 = 32 per row
    int row = i >> 5;
    float4 a = ((const float4*)out)[i];
    float l = Ls[row];
    if (nsplit == 2) {
        float4 c = ((const float4*)O1)[i];
        a.x += c.x; a.y += c.y; a.z += c.z; a.w += c.w;
        l += Ls[B_ * T_ + row];
    }
    float rinv = 1.0f / l;
    a.x *= rinv; a.y *= rinv; a.z *= rinv; a.w *= rinv;
    ((float4*)out)[i] = a;
}

extern "C" void kernel_launch(void* const* d_in, const int* in_sizes, int n_in,
                              void* d_out, int out_size, void* d_ws, size_t ws_size,
                              hipStream_t stream)
{
    const float* x  = (const float*)d_in[0];
    const float* Wk = (const float*)d_in[1];
    const float* Wq = (const float*)d_in[2];
    const float* Wv = (const float*)d_in[3];
    float* out = (float*)d_out;

    const size_t elems = (size_t)B_ * T_ * H_;            // 8.4M elements
    f16* qb  = (f16*)d_ws;                                // f16 q   [B][T][H]  16 MB
    f16* kb  = qb + elems;                                // f16 k   [B][T][H]  16 MB
    f16* vtb = kb + elems;                                // f16 v^T [B][H][T]  16 MB
    float* Ls = (float*)(vtb + elems);                    // [2][B*T] fp32 row sums
    float* O1 = Ls + 2 * (size_t)B_ * T_;                 // split-1 O partial (fp32, 32 MB)

    const size_t need2 = 3 * elems * 2 + 2 * (size_t)B_ * T_ * 4 + elems * 4;
    const int ns = (ws_size >= need2) ? 2 : 1;

    proj_kernel<<<dim3(B_ * 64), dim3(256), 0, stream>>>(x, Wk, Wq, Wv, qb, kb, vtb);
    attn_kernel<<<dim3(T_ / BQ, B_, ns), dim3(256), 0, stream>>>(qb, kb, vtb, out, O1, Ls, ns);
    combine_kernel<<<dim3((int)(elems / 4 / 256)), dim3(256), 0, stream>>>(out, O1, Ls, ns);
}

// Round 5
// 362.098 us; speedup vs baseline: 1.4199x; 1.4199x over previous
//
#include <hip/hip_runtime.h>
#include <stdint.h>

#define B_ 16
#define T_ 4096
#define C_ 64
#define H_ 128
#define BQ 128
#define BK 64
#define VS  72    // proj vt-transpose scratch stride (144 B rows, 16B-aligned)

typedef _Float16 f16;
typedef __attribute__((ext_vector_type(8))) _Float16 half8;   // 4 VGPRs (16x16x32 A/B)
typedef __attribute__((ext_vector_type(4))) _Float16 half4;   // 2 VGPRs (16x16x16 A/B)
typedef __attribute__((ext_vector_type(4))) float   floatx4;  // MFMA C/D frag

__device__ __forceinline__ f16 f2h(float f) { return (f16)f; }

__device__ __forceinline__ float fexp2(float x) {
#if __has_builtin(__builtin_amdgcn_exp2f)
    return __builtin_amdgcn_exp2f(x);
#else
    return exp2f(x);
#endif
}

// async global->LDS, 16 B per lane, dest = wave-uniform base + lane*16
__device__ __forceinline__ void async_cp16(const void* g, void* l) {
    __builtin_amdgcn_global_load_lds(
        (const __attribute__((address_space(1))) unsigned int*)g,
        (__attribute__((address_space(3))) unsigned int*)l, 16, 0, 0);
}

// ---------------------------------------------------------------------------
// Projections: q,k -> f16 [B][T][H]; v -> f16 vt[B][H][T] (transposed)
// ---------------------------------------------------------------------------
__global__ __launch_bounds__(256) void proj_kernel(
    const float* __restrict__ x, const float* __restrict__ Wk,
    const float* __restrict__ Wq, const float* __restrict__ Wv,
    f16* __restrict__ qo, f16* __restrict__ ko, f16* __restrict__ vto)
{
    __shared__ __align__(16) char smem[48 * 1024];
    float* xl = (float*)smem;                       // [64][64] fp32 x tile
    float* wl = (float*)(smem + 16384);             // [64][128] fp32 W
    f16* vtl  = (f16*)(smem + 16384);               // [128][VS] f16 (aliases wl)

    const int tid = threadIdx.x;
    const int b   = blockIdx.x >> 6;
    const int t0  = (blockIdx.x & 63) * 64;

    #pragma unroll
    for (int it = 0; it < 4; ++it) {
        int r = (tid >> 4) + it * 16;
        int c = (tid & 15) * 4;
        *(float4*)&xl[r * 64 + c] =
            *(const float4*)(x + ((size_t)(b * T_ + t0 + r)) * C_ + c);
    }

    const int h0 = (tid & 31) * 4;
    const int rg = tid >> 5;

    for (int m = 0; m < 3; ++m) {
        const float* W = (m == 0) ? Wk : (m == 1) ? Wq : Wv;
        __syncthreads();
        #pragma unroll
        for (int it = 0; it < 8; ++it) {
            int r = (tid >> 5) + it * 8;
            int c = (tid & 31) * 4;
            *(float4*)&wl[r * 128 + c] = *(const float4*)(W + r * 128 + c);
        }
        __syncthreads();

        float acc[8][4];
        #pragma unroll
        for (int i = 0; i < 8; ++i)
            #pragma unroll
            for (int j = 0; j < 4; ++j) acc[i][j] = 0.f;

        #pragma unroll 8
        for (int c = 0; c < 64; ++c) {
            float4 w = *(const float4*)&wl[c * 128 + h0];
            #pragma unroll
            for (int i = 0; i < 8; ++i) {
                float xi = xl[(rg * 8 + i) * 64 + c];
                acc[i][0] += xi * w.x;
                acc[i][1] += xi * w.y;
                acc[i][2] += xi * w.z;
                acc[i][3] += xi * w.w;
            }
        }

        if (m < 2) {
            f16* o = (m == 0) ? ko : qo;
            #pragma unroll
            for (int i = 0; i < 8; ++i) {
                half4 pk = {f2h(acc[i][0]), f2h(acc[i][1]), f2h(acc[i][2]), f2h(acc[i][3])};
                *(half4*)(o + ((size_t)(b * T_ + t0 + rg * 8 + i)) * H_ + h0) = pk;
            }
        } else {
            __syncthreads();
            #pragma unroll
            for (int i = 0; i < 8; ++i)
                #pragma unroll
                for (int c2 = 0; c2 < 4; ++c2)
                    vtl[(h0 + c2) * VS + rg * 8 + i] = f2h(acc[i][c2]);
            __syncthreads();
            int h  = tid >> 1;
            int sg = (tid & 1) * 32;
            int4* dst = (int4*)(vto + ((size_t)(b * H_ + h)) * T_ + t0 + sg);
            const int4* src = (const int4*)&vtl[h * VS + sg];
            dst[0] = src[0]; dst[1] = src[1]; dst[2] = src[2]; dst[3] = src[3];
        }
    }
}

// ---------------------------------------------------------------------------
// Flash attention, chained-MFMA, fully-async staging. Block = 4 waves,
// BQ=128, BK=64, 3 blocks/CU (LDS 48 KB, non-acc regs ~71 < 84 arch budget).
// St = K·Q^T via 16x16x32_f16 (st outer, ks inner -> only 8 S regs live);
// exp2 -> half4 == B-operand of mfma_f32_16x16x16f16 -> PV chained, no P LDS.
// K single-buffered + V double-buffered, both staged via global_load_lds with
// XOR-granule swizzles (2-way max bank aliasing = free). 3 barriers/chunk.
// s-split over blockIdx.z; combine_kernel merges/normalizes.
// ---------------------------------------------------------------------------
__global__ __launch_bounds__(256, 3) void attn_kernel(
    const f16* __restrict__ q,
    const f16* __restrict__ k,
    const f16* __restrict__ vt,
    float* __restrict__ O0, float* __restrict__ O1,
    float* __restrict__ Ls, int nsplit)
{
    __shared__ __align__(16) f16 Kl[64 * 128];      // 16384 B, swizzled granules
    __shared__ __align__(16) f16 Vtl[2][128 * 64];  // 32768 B, swizzled granules

    const int tid  = threadIdx.x;
    const int wave = tid >> 6;
    const int lane = tid & 63;
    const int col  = lane & 15;
    const int quad = lane >> 4;
    const int c7   = col & 7;
    const int qh   = quad >> 1;        // V-read granule select
    const int ql   = (quad & 1) * 4;   // V-read half-of-granule (f16 elems)
    const int b    = blockIdx.y;
    const int q0   = blockIdx.x * BQ;
    const int split  = blockIdx.z;
    const int NC     = T_ / BK / nsplit;
    const int s_base = split * (T_ / nsplit);

    // staging lane constants
    const int klr = lane >> 4;          // K: row-in-slab 0..3
    const int kph = (lane & 15) & 8;    // K: granule pos high bit
    const int kpl = lane & 7;           // K: granule pos low bits
    const int vrow = lane >> 3;         // V: row-in-call 0..7
    const int vswz = (lane & 7) ^ vrow; // V: swizzled source granule

    // Q fragments (reused NC chunks) — B-operand layout [n=lane&15][k=quad*8+j]
    half8 qf[2][4];
    #pragma unroll
    for (int qt = 0; qt < 2; ++qt) {
        const f16* qrow =
            q + ((size_t)(b * T_ + q0 + wave * 32 + qt * 16 + col)) * H_ + quad * 8;
        #pragma unroll
        for (int ks = 0; ks < 4; ++ks)
            qf[qt][ks] = *(const half8*)(qrow + ks * 32);
    }

    floatx4 o[2][8];   // Ot accum: lane holds q=qt*16+col, h=ht*16+quad*4+r
    #pragma unroll
    for (int qt = 0; qt < 2; ++qt)
        #pragma unroll
        for (int ht = 0; ht < 8; ++ht) { o[qt][ht][0]=0.f; o[qt][ht][1]=0.f; o[qt][ht][2]=0.f; o[qt][ht][3]=0.f; }
    float lsum[2] = {0.f, 0.f};

    const float SC = 0.125f * 1.44269504088896340736f;  // scale * log2(e)

    // K staging: 16 slabs of 1 KB (4 rows x 256 B); wave w does slabs w*4..w*4+3.
    // granule g of row r stored at pos p = (g&8)|((g&7)^(r&7)).
    #define ISSUE_K(S0)                                                           \
        do { _Pragma("unroll")                                                    \
            for (int it = 0; it < 4; ++it) {                                      \
                int slab = wave * 4 + it;                                         \
                int r7   = ((slab & 1) * 4 + klr);                                \
                int g    = kph | (kpl ^ r7);                                      \
                async_cp16(k + ((size_t)(b * T_ + (S0) + slab * 4 + klr)) * H_ + g * 8, \
                           (void*)&Kl[slab * 512]);                               \
            }                                                                     \
        } while (0)

    // V staging: 16 slabs of 1 KB (8 rows x 128 B); granule g of row h stored
    // at pos p = g ^ (h&7).
    #define ISSUE_VT(S0, BUF)                                                     \
        do { _Pragma("unroll")                                                    \
            for (int it = 0; it < 4; ++it) {                                      \
                int hbase = wave * 32 + it * 8;                                   \
                async_cp16(vt + ((size_t)(b * H_ + hbase + vrow)) * T_ + (S0) + vswz * 8, \
                           (void*)&Vtl[BUF][hbase * 64]);                         \
            }                                                                     \
        } while (0)

    ISSUE_K(s_base);
    ISSUE_VT(s_base, 0);

    for (int ci = 0; ci < NC; ++ci) {
        const int buf = ci & 1;
        __syncthreads();                       // α: K(ci) + Vt(ci) landed (vmcnt drain)
        if (ci + 1 < NC) ISSUE_VT(s_base + (ci + 1) * BK, buf ^ 1);

        // St = K·Q^T, st outer / ks inner -> exp2 immediately, 8 S regs live.
        // K frag read: row=st*16+col, need granule g=ks*4+quad at
        // pos p = (g&8)|((g&7)^(row&7)); addr f16 = row*128 + p*8.
        half4 pf[2][4];
        #pragma unroll
        for (int st = 0; st < 4; ++st) {
            floatx4 s0 = {0.f, 0.f, 0.f, 0.f};
            floatx4 s1 = {0.f, 0.f, 0.f, 0.f};
            #pragma unroll
            for (int ks = 0; ks < 4; ++ks) {
                int p = ((ks & 2) << 2) | ((((ks & 1) * 4) + quad) ^ c7);
                half8 kf = *(const half8*)&Kl[(st * 16 + col) * 128 + p * 8];
                s0 = __builtin_amdgcn_mfma_f32_16x16x32_f16(kf, qf[0][ks], s0, 0, 0, 0);
                s1 = __builtin_amdgcn_mfma_f32_16x16x32_f16(kf, qf[1][ks], s1, 0, 0, 0);
            }
            float p0 = fexp2(s0[0] * SC), p1 = fexp2(s0[1] * SC);
            float p2 = fexp2(s0[2] * SC), p3 = fexp2(s0[3] * SC);
            lsum[0] += (p0 + p1) + (p2 + p3);
            pf[0][st] = half4{f2h(p0), f2h(p1), f2h(p2), f2h(p3)};
            p0 = fexp2(s1[0] * SC); p1 = fexp2(s1[1] * SC);
            p2 = fexp2(s1[2] * SC); p3 = fexp2(s1[3] * SC);
            lsum[1] += (p0 + p1) + (p2 + p3);
            pf[1][st] = half4{f2h(p0), f2h(p1), f2h(p2), f2h(p3)};
        }

        __syncthreads();                       // γ: all Kl reads done
        if (ci + 1 < NC) ISSUE_K(s_base + (ci + 1) * BK);   // overlaps PV

        // Ot += Vt·P : A = Vt[h=tile col][s=quad*4+j] (b64, swizzled), B = pf.
        #pragma unroll
        for (int sp = 0; sp < 4; ++sp) {
            const int sw = ((((sp * 2 + qh) ^ c7) << 3) + ql) + col * 64;
            #pragma unroll
            for (int ht = 0; ht < 8; ++ht) {
                half4 va = *(const half4*)&Vtl[buf][ht * 1024 + sw];
                o[0][ht] = __builtin_amdgcn_mfma_f32_16x16x16f16(va, pf[0][sp], o[0][ht], 0, 0, 0);
                o[1][ht] = __builtin_amdgcn_mfma_f32_16x16x16f16(va, pf[1][sp], o[1][ht], 0, 0, 0);
            }
        }
    }
    #undef ISSUE_K
    #undef ISSUE_VT

    // epilogue: lane holds O[q=qt*16+col][h=ht*16+quad*4+r] (unnormalized)
    float* Op = (split == 0) ? O0 : O1;
    #pragma unroll
    for (int qt = 0; qt < 2; ++qt) {
        float l = lsum[qt];
        l += __shfl_xor(l, 16);
        l += __shfl_xor(l, 32);
        int qrow = q0 + wave * 32 + qt * 16 + col;
        if (quad == 0)
            Ls[(size_t)split * (B_ * T_) + b * T_ + qrow] = l;
        float* orow = Op + ((size_t)(b * T_ + qrow)) * H_;
        #pragma unroll
        for (int ht = 0; ht < 8; ++ht) {
            float4 st4 = {o[qt][ht][0], o[qt][ht][1], o[qt][ht][2], o[qt][ht][3]};
            *(float4*)&orow[ht * 16 + quad * 4] = st4;
        }
    }
}

// ---------------------------------------------------------------------------
// Merge s-split partials and normalize: out = (O0 [+ O1]) / (l0 [+ l1])
// ---------------------------------------------------------------------------
__global__ __launch_bounds__(256) void combine_kernel(
    float* __restrict__ out, const float* __restrict__ O1,
    const float* __restrict__ Ls, int nsplit)
{
    int i = blockIdx.x * 256 + threadIdx.x;   // float4 index, H/4 = 32 per row
    int row = i >> 5;
    float4 a = ((const float4*)out)[i];
    float l = Ls[row];
    if (nsplit == 2) {
        float4 c = ((const float4*)O1)[i];
        a.x += c.x; a.y += c.y; a.z += c.z; a.w += c.w;
        l += Ls[B_ * T_ + row];
    }
    float rinv = 1.0f / l;
    a.x *= rinv; a.y *= rinv; a.z *= rinv; a.w *= rinv;
    ((float4*)out)[i] = a;
}

extern "C" void kernel_launch(void* const* d_in, const int* in_sizes, int n_in,
                              void* d_out, int out_size, void* d_ws, size_t ws_size,
                              hipStream_t stream)
{
    const float* x  = (const float*)d_in[0];
    const float* Wk = (const float*)d_in[1];
    const float* Wq = (const float*)d_in[2];
    const float* Wv = (const float*)d_in[3];
    float* out = (float*)d_out;

    const size_t elems = (size_t)B_ * T_ * H_;            // 8.4M elements
    f16* qb  = (f16*)d_ws;                                // f16 q   [B][T][H]  16 MB
    f16* kb  = qb + elems;                                // f16 k   [B][T][H]  16 MB
    f16* vtb = kb + elems;                                // f16 v^T [B][H][T]  16 MB
    float* Ls = (float*)(vtb + elems);                    // [2][B*T] fp32 row sums
    float* O1 = Ls + 2 * (size_t)B_ * T_;                 // split-1 O partial (fp32, 32 MB)

    const size_t need2 = 3 * elems * 2 + 2 * (size_t)B_ * T_ * 4 + elems * 4;
    const int ns = (ws_size >= need2) ? 2 : 1;

    proj_kernel<<<dim3(B_ * 64), dim3(256), 0, stream>>>(x, Wk, Wq, Wv, qb, kb, vtb);
    attn_kernel<<<dim3(T_ / BQ, B_, ns), dim3(256), 0, stream>>>(qb, kb, vtb, out, O1, Ls, ns);
    combine_kernel<<<dim3((int)(elems / 4 / 256)), dim3(256), 0, stream>>>(out, O1, Ls, ns);
}

// Round 6
// 295.429 us; speedup vs baseline: 1.7403x; 1.2257x over previous
//
#include <hip/hip_runtime.h>
#include <stdint.h>

#define B_ 16
#define T_ 4096
#define C_ 64
#define H_ 128
#define BQ 128
#define BK 64

typedef _Float16 f16;
typedef __attribute__((ext_vector_type(8))) _Float16 half8;   // 4 VGPRs (16x16x32 A/B)
typedef __attribute__((ext_vector_type(4))) _Float16 half4;   // 2 VGPRs (16x16x16 A/B)
typedef __attribute__((ext_vector_type(4))) float   floatx4;  // MFMA C/D frag

__device__ __forceinline__ f16 f2h(float f) { return (f16)f; }

__device__ __forceinline__ float fexp2(float x) {
#if __has_builtin(__builtin_amdgcn_exp2f)
    return __builtin_amdgcn_exp2f(x);
#else
    return exp2f(x);
#endif
}

// async global->LDS, 16 B per lane, dest = wave-uniform base + lane*16
__device__ __forceinline__ void async_cp16(const void* g, void* l) {
    __builtin_amdgcn_global_load_lds(
        (const __attribute__((address_space(1))) unsigned int*)g,
        (__attribute__((address_space(3))) unsigned int*)l, 16, 0, 0);
}

// ---------------------------------------------------------------------------
// MFMA projections: q,k -> f16 [B][T][H]; v -> f16 vt[B][H][T].
// Per block: 64 t-rows. x fragments go global->regs (fp32->f16); W staged as
// W^T f16 in LDS (stride 80 = 160B rows, 4-way max b128 aliasing); 16 MFMA
// per wave per matrix. q/k epilogue: per-wave LDS transpose -> b128 stores.
// v epilogue: block-wide h-scatter -> b128 stores of vt rows.
// ---------------------------------------------------------------------------
#define WTS 80    // W^T LDS stride (f16)
#define QKS 136   // q/k scratch stride (f16)
#define VTS 72    // vt scratch stride (f16)

__global__ __launch_bounds__(256) void proj_kernel(
    const float* __restrict__ x, const float* __restrict__ Wk,
    const float* __restrict__ Wq, const float* __restrict__ Wv,
    f16* __restrict__ qo, f16* __restrict__ ko, f16* __restrict__ vto)
{
    __shared__ __align__(16) char smem[20480];      // Wt / scratch (aliased by phase)
    f16* Wt  = (f16*)smem;                          // [128 h][WTS]  20480 B
    f16* Sw  = (f16*)smem;                          // per-wave [16][QKS] transpose scratch
    f16* vtl = (f16*)smem;                          // [128 h][VTS]  18432 B

    const int tid  = threadIdx.x;
    const int wave = tid >> 6;
    const int lane = tid & 63;
    const int col  = lane & 15;
    const int quad = lane >> 4;
    const int b    = blockIdx.x >> 6;
    const int t0   = (blockIdx.x & 63) * 64;

    // A-fragments: x rows t0+wave*16+col, K=64 in 2 ks-steps (fp32 -> f16)
    half8 ax[2];
    {
        const float* xr = x + ((size_t)(b * T_ + t0 + wave * 16 + col)) * C_ + quad * 8;
        #pragma unroll
        for (int ks = 0; ks < 2; ++ks) {
            float4 a0 = *(const float4*)(xr + ks * 32);
            float4 a1 = *(const float4*)(xr + ks * 32 + 4);
            ax[ks] = half8{f2h(a0.x), f2h(a0.y), f2h(a0.z), f2h(a0.w),
                           f2h(a1.x), f2h(a1.y), f2h(a1.z), f2h(a1.w)};
        }
    }

    for (int m = 0; m < 3; ++m) {
        const float* W = (m == 0) ? Wk : (m == 1) ? Wq : Wv;
        __syncthreads();   // prior matrix's scratch reads complete
        // stage W^T f16: thread reads W[c][h0..h0+3] fp32 coalesced, scatters
        #pragma unroll
        for (int it = 0; it < 8; ++it) {
            int c  = (tid >> 5) + it * 8;
            int h0 = (tid & 31) * 4;
            float4 w = *(const float4*)(W + c * H_ + h0);
            Wt[(h0 + 0) * WTS + c] = f2h(w.x);
            Wt[(h0 + 1) * WTS + c] = f2h(w.y);
            Wt[(h0 + 2) * WTS + c] = f2h(w.z);
            Wt[(h0 + 3) * WTS + c] = f2h(w.w);
        }
        __syncthreads();

        floatx4 acc[8];
        #pragma unroll
        for (int nt = 0; nt < 8; ++nt) { acc[nt][0]=0.f; acc[nt][1]=0.f; acc[nt][2]=0.f; acc[nt][3]=0.f; }
        #pragma unroll
        for (int nt = 0; nt < 8; ++nt)
            #pragma unroll
            for (int ks = 0; ks < 2; ++ks) {
                half8 bf = *(const half8*)&Wt[(nt * 16 + col) * WTS + ks * 32 + quad * 8];
                acc[nt] = __builtin_amdgcn_mfma_f32_16x16x32_f16(ax[ks], bf, acc[nt], 0, 0, 0);
            }
        __syncthreads();   // all Wt reads done -> scratch may alias

        if (m < 2) {
            // D[t=quad*4+r][h=nt*16+col] -> per-wave transpose -> row-major b128
            f16* S = Sw + wave * 16 * QKS;
            #pragma unroll
            for (int nt = 0; nt < 8; ++nt)
                #pragma unroll
                for (int r = 0; r < 4; ++r)
                    S[(quad * 4 + r) * QKS + nt * 16 + col] = f2h(acc[nt][r]);
            f16* o = (m == 0) ? ko : qo;
            int rw = lane >> 2;
            #pragma unroll
            for (int p = 0; p < 4; ++p) {
                int ck = (lane & 3) + p * 4;             // 16-B chunk 0..15
                half8 d = *(const half8*)&S[rw * QKS + ck * 8];
                *(half8*)(o + ((size_t)(b * T_ + t0 + wave * 16 + rw)) * H_ + ck * 8) = d;
            }
        } else {
            // v: scatter by h into vtl[128][VTS], then copy rows to vt[B][H][T]
            #pragma unroll
            for (int nt = 0; nt < 8; ++nt)
                #pragma unroll
                for (int r = 0; r < 4; ++r)
                    vtl[(nt * 16 + col) * VTS + wave * 16 + quad * 4 + r] = f2h(acc[nt][r]);
            __syncthreads();
            int h  = tid >> 1;
            int sg = (tid & 1) * 32;
            int4* dst = (int4*)(vto + ((size_t)(b * H_ + h)) * T_ + t0 + sg);
            const int4* src = (const int4*)&vtl[h * VTS + sg];
            dst[0] = src[0]; dst[1] = src[1]; dst[2] = src[2]; dst[3] = src[3];
        }
    }
}

// ---------------------------------------------------------------------------
// Flash attention, chained-MFMA, K+V BOTH async double-buffered, ONE barrier
// per chunk: prefetches issue right after the barrier and are drained by the
// NEXT barrier's vmcnt(0) -> a full chunk of latency cover. Block = 4 waves,
// BQ=128, BK=64, LDS 64 KB -> 2 blocks/CU, (256,2) -> no register pressure.
// St = K·Q^T (16x16x32_f16, st outer -> 8 S regs live); exp2 -> half4 ==
// B-operand of mfma_f32_16x16x16f16 -> PV chained with zero P data movement.
// s-split over blockIdx.z; combine_kernel merges/normalizes.
// ---------------------------------------------------------------------------
__global__ __launch_bounds__(256, 2) void attn_kernel(
    const f16* __restrict__ q,
    const f16* __restrict__ k,
    const f16* __restrict__ vt,
    float* __restrict__ O0, float* __restrict__ O1,
    float* __restrict__ Ls, int nsplit)
{
    __shared__ __align__(16) f16 Kl[2][64 * 128];   // 32768 B, swizzled granules
    __shared__ __align__(16) f16 Vtl[2][128 * 64];  // 32768 B, swizzled granules

    const int tid  = threadIdx.x;
    const int wave = tid >> 6;
    const int lane = tid & 63;
    const int col  = lane & 15;
    const int quad = lane >> 4;
    const int c7   = col & 7;
    const int qh   = quad >> 1;        // V-read granule select
    const int ql   = (quad & 1) * 4;   // V-read half-of-granule (f16 elems)
    const int b    = blockIdx.y;
    const int q0   = blockIdx.x * BQ;
    const int split  = blockIdx.z;
    const int NC     = T_ / BK / nsplit;
    const int s_base = split * (T_ / nsplit);

    // staging lane constants
    const int klr = lane >> 4;          // K: row-in-slab 0..3
    const int kph = (lane & 15) & 8;    // K: granule pos high bit
    const int kpl = lane & 7;           // K: granule pos low bits
    const int vrow = lane >> 3;         // V: row-in-call 0..7
    const int vswz = (lane & 7) ^ vrow; // V: swizzled source granule

    // Q fragments (reused NC chunks) — B-operand layout [n=lane&15][k=quad*8+j]
    half8 qf[2][4];
    #pragma unroll
    for (int qt = 0; qt < 2; ++qt) {
        const f16* qrow =
            q + ((size_t)(b * T_ + q0 + wave * 32 + qt * 16 + col)) * H_ + quad * 8;
        #pragma unroll
        for (int ks = 0; ks < 4; ++ks)
            qf[qt][ks] = *(const half8*)(qrow + ks * 32);
    }

    floatx4 o[2][8];   // Ot accum: lane holds q=qt*16+col, h=ht*16+quad*4+r
    #pragma unroll
    for (int qt = 0; qt < 2; ++qt)
        #pragma unroll
        for (int ht = 0; ht < 8; ++ht) { o[qt][ht][0]=0.f; o[qt][ht][1]=0.f; o[qt][ht][2]=0.f; o[qt][ht][3]=0.f; }
    float lsum[2] = {0.f, 0.f};

    const float SC = 0.125f * 1.44269504088896340736f;  // scale * log2(e)

    // K staging: 16 slabs of 1 KB (4 rows x 256 B); wave w does slabs w*4..w*4+3.
    // granule g of row r stored at pos p = (g&8)|((g&7)^(r&7)).
    #define ISSUE_K(S0, BUF)                                                      \
        do { _Pragma("unroll")                                                    \
            for (int it = 0; it < 4; ++it) {                                      \
                int slab = wave * 4 + it;                                         \
                int r7   = ((slab & 1) * 4 + klr);                                \
                int g    = kph | (kpl ^ r7);                                      \
                async_cp16(k + ((size_t)(b * T_ + (S0) + slab * 4 + klr)) * H_ + g * 8, \
                           (void*)&Kl[BUF][slab * 512]);                          \
            }                                                                     \
        } while (0)

    // V staging: 16 slabs of 1 KB (8 rows x 128 B); granule g of row h stored
    // at pos p = g ^ (h&7).
    #define ISSUE_VT(S0, BUF)                                                     \
        do { _Pragma("unroll")                                                    \
            for (int it = 0; it < 4; ++it) {                                      \
                int hbase = wave * 32 + it * 8;                                   \
                async_cp16(vt + ((size_t)(b * H_ + hbase + vrow)) * T_ + (S0) + vswz * 8, \
                           (void*)&Vtl[BUF][hbase * 64]);                         \
            }                                                                     \
        } while (0)

    ISSUE_K(s_base, 0);
    ISSUE_VT(s_base, 0);

    for (int ci = 0; ci < NC; ++ci) {
        const int buf = ci & 1;
        __syncthreads();   // vmcnt(0)+barrier: K(ci),V(ci) landed; buf^1 reads done
        if (ci + 1 < NC) {
            ISSUE_VT(s_base + (ci + 1) * BK, buf ^ 1);
            ISSUE_K(s_base + (ci + 1) * BK, buf ^ 1);
        }

        // St = K·Q^T, st outer / ks inner -> exp2 immediately, 8 S regs live.
        // K frag: row=st*16+col, granule g=ks*4+quad at p=(g&8)|((g&7)^(row&7)).
        half4 pf[2][4];
        #pragma unroll
        for (int st = 0; st < 4; ++st) {
            floatx4 s0 = {0.f, 0.f, 0.f, 0.f};
            floatx4 s1 = {0.f, 0.f, 0.f, 0.f};
            #pragma unroll
            for (int ks = 0; ks < 4; ++ks) {
                int p = ((ks & 2) << 2) | ((((ks & 1) * 4) + quad) ^ c7);
                half8 kf = *(const half8*)&Kl[buf][(st * 16 + col) * 128 + p * 8];
                s0 = __builtin_amdgcn_mfma_f32_16x16x32_f16(kf, qf[0][ks], s0, 0, 0, 0);
                s1 = __builtin_amdgcn_mfma_f32_16x16x32_f16(kf, qf[1][ks], s1, 0, 0, 0);
            }
            float p0 = fexp2(s0[0] * SC), p1 = fexp2(s0[1] * SC);
            float p2 = fexp2(s0[2] * SC), p3 = fexp2(s0[3] * SC);
            lsum[0] += (p0 + p1) + (p2 + p3);
            pf[0][st] = half4{f2h(p0), f2h(p1), f2h(p2), f2h(p3)};
            p0 = fexp2(s1[0] * SC); p1 = fexp2(s1[1] * SC);
            p2 = fexp2(s1[2] * SC); p3 = fexp2(s1[3] * SC);
            lsum[1] += (p0 + p1) + (p2 + p3);
            pf[1][st] = half4{f2h(p0), f2h(p1), f2h(p2), f2h(p3)};
        }

        // Ot += Vt·P : A = Vt[h=tile col][s=quad*4+j] (b64, swizzled), B = pf.
        #pragma unroll
        for (int sp = 0; sp < 4; ++sp) {
            const int sw = ((((sp * 2 + qh) ^ c7) << 3) + ql) + col * 64;
            #pragma unroll
            for (int ht = 0; ht < 8; ++ht) {
                half4 va = *(const half4*)&Vtl[buf][ht * 1024 + sw];
                o[0][ht] = __builtin_amdgcn_mfma_f32_16x16x16f16(va, pf[0][sp], o[0][ht], 0, 0, 0);
                o[1][ht] = __builtin_amdgcn_mfma_f32_16x16x16f16(va, pf[1][sp], o[1][ht], 0, 0, 0);
            }
        }
    }
    #undef ISSUE_K
    #undef ISSUE_VT

    // epilogue: lane holds O[q=qt*16+col][h=ht*16+quad*4+r] (unnormalized)
    float* Op = (split == 0) ? O0 : O1;
    #pragma unroll
    for (int qt = 0; qt < 2; ++qt) {
        float l = lsum[qt];
        l += __shfl_xor(l, 16);
        l += __shfl_xor(l, 32);
        int qrow = q0 + wave * 32 + qt * 16 + col;
        if (quad == 0)
            Ls[(size_t)split * (B_ * T_) + b * T_ + qrow] = l;
        float* orow = Op + ((size_t)(b * T_ + qrow)) * H_;
        #pragma unroll
        for (int ht = 0; ht < 8; ++ht) {
            float4 st4 = {o[qt][ht][0], o[qt][ht][1], o[qt][ht][2], o[qt][ht][3]};
            *(float4*)&orow[ht * 16 + quad * 4] = st4;
        }
    }
}

// ---------------------------------------------------------------------------
// Merge s-split partials and normalize: out = (O0 [+ O1]) / (l0 [+ l1])
// ---------------------------------------------------------------------------
__global__ __launch_bounds__(256) void combine_kernel(
    float* __restrict__ out, const float* __restrict__ O1,
    const float* __restrict__ Ls, int nsplit)
{
    int i = blockIdx.x * 256 + threadIdx.x;   // float4 index, H/4 = 32 per row
    int row = i >> 5;
    float4 a = ((const float4*)out)[i];
    float l = Ls[row];
    if (nsplit == 2) {
        float4 c = ((const float4*)O1)[i];
        a.x += c.x; a.y += c.y; a.z += c.z; a.w += c.w;
        l += Ls[B_ * T_ + row];
    }
    float rinv = 1.0f / l;
    a.x *= rinv; a.y *= rinv; a.z *= rinv; a.w *= rinv;
    ((float4*)out)[i] = a;
}

extern "C" void kernel_launch(void* const* d_in, const int* in_sizes, int n_in,
                              void* d_out, int out_size, void* d_ws, size_t ws_size,
                              hipStream_t stream)
{
    const float* x  = (const float*)d_in[0];
    const float* Wk = (const float*)d_in[1];
    const float* Wq = (const float*)d_in[2];
    const float* Wv = (const float*)d_in[3];
    float* out = (float*)d_out;

    const size_t elems = (size_t)B_ * T_ * H_;            // 8.4M elements
    f16* qb  = (f16*)d_ws;                                // f16 q   [B][T][H]  16 MB
    f16* kb  = qb + elems;                                // f16 k   [B][T][H]  16 MB
    f16* vtb = kb + elems;                                // f16 v^T [B][H][T]  16 MB
    float* Ls = (float*)(vtb + elems);                    // [2][B*T] fp32 row sums
    float* O1 = Ls + 2 * (size_t)B_ * T_;                 // split-1 O partial (fp32, 32 MB)

    const size_t need2 = 3 * elems * 2 + 2 * (size_t)B_ * T_ * 4 + elems * 4;
    const int ns = (ws_size >= need2) ? 2 : 1;

    proj_kernel<<<dim3(B_ * 64), dim3(256), 0, stream>>>(x, Wk, Wq, Wv, qb, kb, vtb);
    attn_kernel<<<dim3(T_ / BQ, B_, ns), dim3(256), 0, stream>>>(qb, kb, vtb, out, O1, Ls, ns);
    combine_kernel<<<dim3((int)(elems / 4 / 256)), dim3(256), 0, stream>>>(out, O1, Ls, ns);
}

// Round 7
// 295.074 us; speedup vs baseline: 1.7424x; 1.0012x over previous
//
#include <hip/hip_runtime.h>
#include <stdint.h>

#define B_ 16
#define T_ 4096
#define C_ 64
#define H_ 128
#define BQ 128
#define BK 64

typedef _Float16 f16;
typedef __attribute__((ext_vector_type(8))) _Float16 half8;   // 4 VGPRs (16x16x32 A/B)
typedef __attribute__((ext_vector_type(4))) _Float16 half4;   // 2 VGPRs
typedef __attribute__((ext_vector_type(4))) float   floatx4;  // MFMA C/D frag

__device__ __forceinline__ f16 f2h(float f) { return (f16)f; }

__device__ __forceinline__ float fexp2(float x) {
#if __has_builtin(__builtin_amdgcn_exp2f)
    return __builtin_amdgcn_exp2f(x);
#else
    return exp2f(x);
#endif
}

// async global->LDS, 16 B per lane, dest = wave-uniform base + lane*16
__device__ __forceinline__ void async_cp16(const void* g, void* l) {
    __builtin_amdgcn_global_load_lds(
        (const __attribute__((address_space(1))) unsigned int*)g,
        (__attribute__((address_space(3))) unsigned int*)l, 16, 0, 0);
}

// ---------------------------------------------------------------------------
// MFMA projections: q,k -> f16 [B][T][H]; v -> f16 vt[B][H][T].
// ---------------------------------------------------------------------------
#define WTS 80    // W^T LDS stride (f16)
#define QKS 136   // q/k scratch stride (f16)
#define VTS 72    // vt scratch stride (f16)

__global__ __launch_bounds__(256) void proj_kernel(
    const float* __restrict__ x, const float* __restrict__ Wk,
    const float* __restrict__ Wq, const float* __restrict__ Wv,
    f16* __restrict__ qo, f16* __restrict__ ko, f16* __restrict__ vto)
{
    __shared__ __align__(16) char smem[20480];      // Wt / scratch (aliased by phase)
    f16* Wt  = (f16*)smem;                          // [128 h][WTS]  20480 B
    f16* Sw  = (f16*)smem;                          // per-wave [16][QKS] transpose scratch
    f16* vtl = (f16*)smem;                          // [128 h][VTS]  18432 B

    const int tid  = threadIdx.x;
    const int wave = tid >> 6;
    const int lane = tid & 63;
    const int col  = lane & 15;
    const int quad = lane >> 4;
    const int b    = blockIdx.x >> 6;
    const int t0   = (blockIdx.x & 63) * 64;

    // A-fragments: x rows t0+wave*16+col, K=64 in 2 ks-steps (fp32 -> f16)
    half8 ax[2];
    {
        const float* xr = x + ((size_t)(b * T_ + t0 + wave * 16 + col)) * C_ + quad * 8;
        #pragma unroll
        for (int ks = 0; ks < 2; ++ks) {
            float4 a0 = *(const float4*)(xr + ks * 32);
            float4 a1 = *(const float4*)(xr + ks * 32 + 4);
            ax[ks] = half8{f2h(a0.x), f2h(a0.y), f2h(a0.z), f2h(a0.w),
                           f2h(a1.x), f2h(a1.y), f2h(a1.z), f2h(a1.w)};
        }
    }

    for (int m = 0; m < 3; ++m) {
        const float* W = (m == 0) ? Wk : (m == 1) ? Wq : Wv;
        __syncthreads();   // prior matrix's scratch reads complete
        #pragma unroll
        for (int it = 0; it < 8; ++it) {
            int c  = (tid >> 5) + it * 8;
            int h0 = (tid & 31) * 4;
            float4 w = *(const float4*)(W + c * H_ + h0);
            Wt[(h0 + 0) * WTS + c] = f2h(w.x);
            Wt[(h0 + 1) * WTS + c] = f2h(w.y);
            Wt[(h0 + 2) * WTS + c] = f2h(w.z);
            Wt[(h0 + 3) * WTS + c] = f2h(w.w);
        }
        __syncthreads();

        floatx4 acc[8];
        #pragma unroll
        for (int nt = 0; nt < 8; ++nt) { acc[nt][0]=0.f; acc[nt][1]=0.f; acc[nt][2]=0.f; acc[nt][3]=0.f; }
        #pragma unroll
        for (int nt = 0; nt < 8; ++nt)
            #pragma unroll
            for (int ks = 0; ks < 2; ++ks) {
                half8 bf = *(const half8*)&Wt[(nt * 16 + col) * WTS + ks * 32 + quad * 8];
                acc[nt] = __builtin_amdgcn_mfma_f32_16x16x32_f16(ax[ks], bf, acc[nt], 0, 0, 0);
            }
        __syncthreads();   // all Wt reads done -> scratch may alias

        if (m < 2) {
            f16* S = Sw + wave * 16 * QKS;
            #pragma unroll
            for (int nt = 0; nt < 8; ++nt)
                #pragma unroll
                for (int r = 0; r < 4; ++r)
                    S[(quad * 4 + r) * QKS + nt * 16 + col] = f2h(acc[nt][r]);
            f16* o = (m == 0) ? ko : qo;
            int rw = lane >> 2;
            #pragma unroll
            for (int p = 0; p < 4; ++p) {
                int ck = (lane & 3) + p * 4;
                half8 d = *(const half8*)&S[rw * QKS + ck * 8];
                *(half8*)(o + ((size_t)(b * T_ + t0 + wave * 16 + rw)) * H_ + ck * 8) = d;
            }
        } else {
            #pragma unroll
            for (int nt = 0; nt < 8; ++nt)
                #pragma unroll
                for (int r = 0; r < 4; ++r)
                    vtl[(nt * 16 + col) * VTS + wave * 16 + quad * 4 + r] = f2h(acc[nt][r]);
            __syncthreads();
            int h  = tid >> 1;
            int sg = (tid & 1) * 32;
            int4* dst = (int4*)(vto + ((size_t)(b * H_ + h)) * T_ + t0 + sg);
            const int4* src = (const int4*)&vtl[h * VTS + sg];
            dst[0] = src[0]; dst[1] = src[1]; dst[2] = src[2]; dst[3] = src[3];
        }
    }
}

// ---------------------------------------------------------------------------
// Flash attention, all-x32 MFMA. Block = 4 waves, BQ=128, BK=64, no s-split
// (grid 512 = exactly 2 blocks/CU resident). K+V async double-buffered, one
// barrier/chunk. St = K·Q^T (x32, st outer). exp2 -> C-layout half4 frags;
// PV at x32: the 8-wide B operand (k=quad*8+j) is assembled from two source
// quads' half4 frags via ds_bpermute (8 pulls + 4 selects per (sp32,qt)).
// V reads become full-granule b128 (conflict-free under the XOR swizzle).
// lsum completes in-kernel -> normalize in epilogue, no combine pass.
// ---------------------------------------------------------------------------
__global__ __launch_bounds__(256, 2) void attn_kernel(
    const f16* __restrict__ q,
    const f16* __restrict__ k,
    const f16* __restrict__ vt,
    float* __restrict__ out)
{
    __shared__ __align__(16) f16 Kl[2][64 * 128];   // 32768 B, swizzled granules
    __shared__ __align__(16) f16 Vtl[2][128 * 64];  // 32768 B, swizzled granules

    const int tid  = threadIdx.x;
    const int wave = tid >> 6;
    const int lane = tid & 63;
    const int col  = lane & 15;
    const int quad = lane >> 4;
    const int c7   = col & 7;
    const int b    = blockIdx.y;
    const int q0   = blockIdx.x * BQ;
    const int NC   = T_ / BK;

    // bpermute source addresses: lo pull = lane (col, 2*(quad&1)),
    // hi pull = lane (col, 2*(quad&1)+1)  [byte addr = lane*4]
    const int addr_lo = ((lane & 15) | ((lane & 16) << 1)) << 2;
    const int addr_hi = addr_lo + 64;

    // staging lane constants
    const int klr = lane >> 4;          // K: row-in-slab 0..3
    const int kph = (lane & 15) & 8;    // K: granule pos high bit
    const int kpl = lane & 7;           // K: granule pos low bits
    const int vrow = lane >> 3;         // V: row-in-call 0..7
    const int vswz = (lane & 7) ^ vrow; // V: swizzled source granule

    // Q fragments (reused NC chunks) — B-operand layout [n=lane&15][k=quad*8+j]
    half8 qf[2][4];
    #pragma unroll
    for (int qt = 0; qt < 2; ++qt) {
        const f16* qrow =
            q + ((size_t)(b * T_ + q0 + wave * 32 + qt * 16 + col)) * H_ + quad * 8;
        #pragma unroll
        for (int ks = 0; ks < 4; ++ks)
            qf[qt][ks] = *(const half8*)(qrow + ks * 32);
    }

    floatx4 o[2][8];   // Ot accum: lane holds q=qt*16+col, h=ht*16+quad*4+r
    #pragma unroll
    for (int qt = 0; qt < 2; ++qt)
        #pragma unroll
        for (int ht = 0; ht < 8; ++ht) { o[qt][ht][0]=0.f; o[qt][ht][1]=0.f; o[qt][ht][2]=0.f; o[qt][ht][3]=0.f; }
    float lsum[2] = {0.f, 0.f};

    const float SC = 0.125f * 1.44269504088896340736f;  // scale * log2(e)

    #define ISSUE_K(S0, BUF)                                                      \
        do { _Pragma("unroll")                                                    \
            for (int it = 0; it < 4; ++it) {                                      \
                int slab = wave * 4 + it;                                         \
                int r7   = ((slab & 1) * 4 + klr);                                \
                int g    = kph | (kpl ^ r7);                                      \
                async_cp16(k + ((size_t)(b * T_ + (S0) + slab * 4 + klr)) * H_ + g * 8, \
                           (void*)&Kl[BUF][slab * 512]);                          \
            }                                                                     \
        } while (0)

    #define ISSUE_VT(S0, BUF)                                                     \
        do { _Pragma("unroll")                                                    \
            for (int it = 0; it < 4; ++it) {                                      \
                int hbase = wave * 32 + it * 8;                                   \
                async_cp16(vt + ((size_t)(b * H_ + hbase + vrow)) * T_ + (S0) + vswz * 8, \
                           (void*)&Vtl[BUF][hbase * 64]);                         \
            }                                                                     \
        } while (0)

    ISSUE_K(0, 0);
    ISSUE_VT(0, 0);

    for (int ci = 0; ci < NC; ++ci) {
        const int buf = ci & 1;
        const int s0c = ci * BK;
        __syncthreads();   // vmcnt(0)+barrier: K(ci),V(ci) landed; buf^1 reads done
        if (ci + 1 < NC) {
            ISSUE_VT(s0c + BK, buf ^ 1);
            ISSUE_K(s0c + BK, buf ^ 1);
        }

        // St = K·Q^T, st outer / ks inner -> exp2 immediately, 8 S regs live.
        half4 pf[2][4];
        #pragma unroll
        for (int st = 0; st < 4; ++st) {
            floatx4 s0 = {0.f, 0.f, 0.f, 0.f};
            floatx4 s1 = {0.f, 0.f, 0.f, 0.f};
            #pragma unroll
            for (int ks = 0; ks < 4; ++ks) {
                int p = ((ks & 2) << 2) | ((((ks & 1) * 4) + quad) ^ c7);
                half8 kf = *(const half8*)&Kl[buf][(st * 16 + col) * 128 + p * 8];
                s0 = __builtin_amdgcn_mfma_f32_16x16x32_f16(kf, qf[0][ks], s0, 0, 0, 0);
                s1 = __builtin_amdgcn_mfma_f32_16x16x32_f16(kf, qf[1][ks], s1, 0, 0, 0);
            }
            float p0 = fexp2(s0[0] * SC), p1 = fexp2(s0[1] * SC);
            float p2 = fexp2(s0[2] * SC), p3 = fexp2(s0[3] * SC);
            lsum[0] += (p0 + p1) + (p2 + p3);
            pf[0][st] = half4{f2h(p0), f2h(p1), f2h(p2), f2h(p3)};
            p0 = fexp2(s1[0] * SC); p1 = fexp2(s1[1] * SC);
            p2 = fexp2(s1[2] * SC); p3 = fexp2(s1[3] * SC);
            lsum[1] += (p0 + p1) + (p2 + p3);
            pf[1][st] = half4{f2h(p0), f2h(p1), f2h(p2), f2h(p3)};
        }

        // PV at x32: assemble 8-wide P (k=quad*8+j over a 32-s double tile)
        // via bpermute; V read = one full 16B granule per lane (conflict-free).
        #pragma unroll
        for (int sp32 = 0; sp32 < 2; ++sp32) {
            half8 p8[2];
            #pragma unroll
            for (int qt = 0; qt < 2; ++qt) {
                union { half4 h; int i[2]; } ta, tb;
                ta.h = pf[qt][sp32 * 2];        // tile for target quads 0,1
                tb.h = pf[qt][sp32 * 2 + 1];    // tile for target quads 2,3
                int la0 = __builtin_amdgcn_ds_bpermute(addr_lo, ta.i[0]);
                int la1 = __builtin_amdgcn_ds_bpermute(addr_lo, ta.i[1]);
                int ha0 = __builtin_amdgcn_ds_bpermute(addr_hi, ta.i[0]);
                int ha1 = __builtin_amdgcn_ds_bpermute(addr_hi, ta.i[1]);
                int lb0 = __builtin_amdgcn_ds_bpermute(addr_lo, tb.i[0]);
                int lb1 = __builtin_amdgcn_ds_bpermute(addr_lo, tb.i[1]);
                int hb0 = __builtin_amdgcn_ds_bpermute(addr_hi, tb.i[0]);
                int hb1 = __builtin_amdgcn_ds_bpermute(addr_hi, tb.i[1]);
                union { int i[4]; half8 h; } r;
                r.i[0] = (quad & 2) ? lb0 : la0;
                r.i[1] = (quad & 2) ? lb1 : la1;
                r.i[2] = (quad & 2) ? hb0 : ha0;
                r.i[3] = (quad & 2) ? hb1 : ha1;
                p8[qt] = r.h;
            }
            #pragma unroll
            for (int ht = 0; ht < 8; ++ht) {
                int pos = (sp32 * 4 + quad) ^ c7;   // stored granule position
                half8 va = *(const half8*)&Vtl[buf][ht * 1024 + col * 64 + pos * 8];
                o[0][ht] = __builtin_amdgcn_mfma_f32_16x16x32_f16(va, p8[0], o[0][ht], 0, 0, 0);
                o[1][ht] = __builtin_amdgcn_mfma_f32_16x16x32_f16(va, p8[1], o[1][ht], 0, 0, 0);
            }
        }
    }
    #undef ISSUE_K
    #undef ISSUE_VT

    // epilogue: reduce lsum across quads, normalize, store final fp32
    #pragma unroll
    for (int qt = 0; qt < 2; ++qt) {
        float l = lsum[qt];
        l += __shfl_xor(l, 16);
        l += __shfl_xor(l, 32);
        float rinv = 1.0f / l;
        int qrow = q0 + wave * 32 + qt * 16 + col;
        float* orow = out + ((size_t)(b * T_ + qrow)) * H_;
        #pragma unroll
        for (int ht = 0; ht < 8; ++ht) {
            float4 st4 = {o[qt][ht][0] * rinv, o[qt][ht][1] * rinv,
                          o[qt][ht][2] * rinv, o[qt][ht][3] * rinv};
            *(float4*)&orow[ht * 16 + quad * 4] = st4;
        }
    }
}

extern "C" void kernel_launch(void* const* d_in, const int* in_sizes, int n_in,
                              void* d_out, int out_size, void* d_ws, size_t ws_size,
                              hipStream_t stream)
{
    const float* x  = (const float*)d_in[0];
    const float* Wk = (const float*)d_in[1];
    const float* Wq = (const float*)d_in[2];
    const float* Wv = (const float*)d_in[3];
    float* out = (float*)d_out;

    const size_t elems = (size_t)B_ * T_ * H_;            // 8.4M elements
    f16* qb  = (f16*)d_ws;                                // f16 q   [B][T][H]  16 MB
    f16* kb  = qb + elems;                                // f16 k   [B][T][H]  16 MB
    f16* vtb = kb + elems;                                // f16 v^T [B][H][T]  16 MB

    proj_kernel<<<dim3(B_ * 64), dim3(256), 0, stream>>>(x, Wk, Wq, Wv, qb, kb, vtb);
    attn_kernel<<<dim3(T_ / BQ, B_), dim3(256), 0, stream>>>(qb, kb, vtb, out);
}

// Round 8
// 280.656 us; speedup vs baseline: 1.8319x; 1.0514x over previous
//
#include <hip/hip_runtime.h>
#include <stdint.h>

#define B_ 16
#define T_ 4096
#define C_ 64
#define H_ 128
#define BQ 128
#define BK 64

typedef _Float16 f16;
typedef __attribute__((ext_vector_type(8))) _Float16 half8;   // 4 VGPRs (16x16x32 A/B)
typedef __attribute__((ext_vector_type(4))) _Float16 half4;   // 2 VGPRs
typedef __attribute__((ext_vector_type(4))) float   floatx4;  // MFMA C/D frag

__device__ __forceinline__ f16 f2h(float f) { return (f16)f; }

__device__ __forceinline__ float fexp2(float x) {
#if __has_builtin(__builtin_amdgcn_exp2f)
    return __builtin_amdgcn_exp2f(x);
#else
    return exp2f(x);
#endif
}

// async global->LDS, 16 B per lane, dest = wave-uniform base + lane*16
__device__ __forceinline__ void async_cp16(const void* g, void* l) {
    __builtin_amdgcn_global_load_lds(
        (const __attribute__((address_space(1))) unsigned int*)g,
        (__attribute__((address_space(3))) unsigned int*)l, 16, 0, 0);
}

// ---------------------------------------------------------------------------
// MFMA projections: q,k -> f16 [B][T][H]; v -> f16 vt[B][H][T].
// ---------------------------------------------------------------------------
#define WTS 80    // W^T LDS stride (f16)
#define QKS 136   // q/k scratch stride (f16)
#define VTS 72    // vt scratch stride (f16)

__global__ __launch_bounds__(256) void proj_kernel(
    const float* __restrict__ x, const float* __restrict__ Wk,
    const float* __restrict__ Wq, const float* __restrict__ Wv,
    f16* __restrict__ qo, f16* __restrict__ ko, f16* __restrict__ vto)
{
    __shared__ __align__(16) char smem[20480];      // Wt / scratch (aliased by phase)
    f16* Wt  = (f16*)smem;                          // [128 h][WTS]  20480 B
    f16* Sw  = (f16*)smem;                          // per-wave [16][QKS] transpose scratch
    f16* vtl = (f16*)smem;                          // [128 h][VTS]  18432 B

    const int tid  = threadIdx.x;
    const int wave = tid >> 6;
    const int lane = tid & 63;
    const int col  = lane & 15;
    const int quad = lane >> 4;
    const int b    = blockIdx.x >> 6;
    const int t0   = (blockIdx.x & 63) * 64;

    // A-fragments: x rows t0+wave*16+col, K=64 in 2 ks-steps (fp32 -> f16)
    half8 ax[2];
    {
        const float* xr = x + ((size_t)(b * T_ + t0 + wave * 16 + col)) * C_ + quad * 8;
        #pragma unroll
        for (int ks = 0; ks < 2; ++ks) {
            float4 a0 = *(const float4*)(xr + ks * 32);
            float4 a1 = *(const float4*)(xr + ks * 32 + 4);
            ax[ks] = half8{f2h(a0.x), f2h(a0.y), f2h(a0.z), f2h(a0.w),
                           f2h(a1.x), f2h(a1.y), f2h(a1.z), f2h(a1.w)};
        }
    }

    for (int m = 0; m < 3; ++m) {
        const float* W = (m == 0) ? Wk : (m == 1) ? Wq : Wv;
        __syncthreads();   // prior matrix's scratch reads complete
        #pragma unroll
        for (int it = 0; it < 8; ++it) {
            int c  = (tid >> 5) + it * 8;
            int h0 = (tid & 31) * 4;
            float4 w = *(const float4*)(W + c * H_ + h0);
            Wt[(h0 + 0) * WTS + c] = f2h(w.x);
            Wt[(h0 + 1) * WTS + c] = f2h(w.y);
            Wt[(h0 + 2) * WTS + c] = f2h(w.z);
            Wt[(h0 + 3) * WTS + c] = f2h(w.w);
        }
        __syncthreads();

        floatx4 acc[8];
        #pragma unroll
        for (int nt = 0; nt < 8; ++nt) { acc[nt][0]=0.f; acc[nt][1]=0.f; acc[nt][2]=0.f; acc[nt][3]=0.f; }
        #pragma unroll
        for (int nt = 0; nt < 8; ++nt)
            #pragma unroll
            for (int ks = 0; ks < 2; ++ks) {
                half8 bf = *(const half8*)&Wt[(nt * 16 + col) * WTS + ks * 32 + quad * 8];
                acc[nt] = __builtin_amdgcn_mfma_f32_16x16x32_f16(ax[ks], bf, acc[nt], 0, 0, 0);
            }
        __syncthreads();   // all Wt reads done -> scratch may alias

        if (m < 2) {
            f16* S = Sw + wave * 16 * QKS;
            #pragma unroll
            for (int nt = 0; nt < 8; ++nt)
                #pragma unroll
                for (int r = 0; r < 4; ++r)
                    S[(quad * 4 + r) * QKS + nt * 16 + col] = f2h(acc[nt][r]);
            f16* o = (m == 0) ? ko : qo;
            int rw = lane >> 2;
            #pragma unroll
            for (int p = 0; p < 4; ++p) {
                int ck = (lane & 3) + p * 4;
                half8 d = *(const half8*)&S[rw * QKS + ck * 8];
                *(half8*)(o + ((size_t)(b * T_ + t0 + wave * 16 + rw)) * H_ + ck * 8) = d;
            }
        } else {
            #pragma unroll
            for (int nt = 0; nt < 8; ++nt)
                #pragma unroll
                for (int r = 0; r < 4; ++r)
                    vtl[(nt * 16 + col) * VTS + wave * 16 + quad * 4 + r] = f2h(acc[nt][r]);
            __syncthreads();
            int h  = tid >> 1;
            int sg = (tid & 1) * 32;
            int4* dst = (int4*)(vto + ((size_t)(b * H_ + h)) * T_ + t0 + sg);
            const int4* src = (const int4*)&vtl[h * VTS + sg];
            dst[0] = src[0]; dst[1] = src[1]; dst[2] = src[2]; dst[3] = src[3];
        }
    }
}

// ---------------------------------------------------------------------------
// Flash attention, all-x32 MFMA, zero cross-lane P movement. Block = 4 waves,
// BQ=128, BK=64, grid 512 (= 2 blocks/CU resident). K+V async double-buffered
// via global_load_lds, one barrier/chunk (full-chunk latency cover).
// St = K·Q^T (x32, st outer -> 8 S regs live); exp2 -> C-layout half4 frags.
// PV at x32 with a PERMUTED s-order: s(k=quad*8+j) =
// (j<4 ? 2*sp32 : 2*sp32+1)*16 + quad*4 + (j&3). Valid because P and V agree
// on the order. B-operand = concat of the lane's own two half4 P-frags
// (pure register concat); A-operand = two swizzled b64 V reads.
// lsum completes in-kernel -> normalize in epilogue, no combine pass.
// ---------------------------------------------------------------------------
__global__ __launch_bounds__(256, 2) void attn_kernel(
    const f16* __restrict__ q,
    const f16* __restrict__ k,
    const f16* __restrict__ vt,
    float* __restrict__ out)
{
    __shared__ __align__(16) f16 Kl[2][64 * 128];   // 32768 B, swizzled granules
    __shared__ __align__(16) f16 Vtl[2][128 * 64];  // 32768 B, swizzled granules

    const int tid  = threadIdx.x;
    const int wave = tid >> 6;
    const int lane = tid & 63;
    const int col  = lane & 15;
    const int quad = lane >> 4;
    const int c7   = col & 7;
    const int qh   = quad >> 1;        // V-read granule select
    const int ql   = (quad & 1) * 4;   // V-read half-of-granule (f16 elems)
    const int b    = blockIdx.y;
    const int q0   = blockIdx.x * BQ;
    const int NC   = T_ / BK;

    // staging lane constants
    const int klr = lane >> 4;          // K: row-in-slab 0..3
    const int kph = (lane & 15) & 8;    // K: granule pos high bit
    const int kpl = lane & 7;           // K: granule pos low bits
    const int vrow = lane >> 3;         // V: row-in-call 0..7
    const int vswz = (lane & 7) ^ vrow; // V: swizzled source granule

    // Q fragments (reused NC chunks) — B-operand layout [n=lane&15][k=quad*8+j]
    half8 qf[2][4];
    #pragma unroll
    for (int qt = 0; qt < 2; ++qt) {
        const f16* qrow =
            q + ((size_t)(b * T_ + q0 + wave * 32 + qt * 16 + col)) * H_ + quad * 8;
        #pragma unroll
        for (int ks = 0; ks < 4; ++ks)
            qf[qt][ks] = *(const half8*)(qrow + ks * 32);
    }

    floatx4 o[2][8];   // Ot accum: lane holds q=qt*16+col, h=ht*16+quad*4+r
    #pragma unroll
    for (int qt = 0; qt < 2; ++qt)
        #pragma unroll
        for (int ht = 0; ht < 8; ++ht) { o[qt][ht][0]=0.f; o[qt][ht][1]=0.f; o[qt][ht][2]=0.f; o[qt][ht][3]=0.f; }
    float lsum[2] = {0.f, 0.f};

    const float SC = 0.125f * 1.44269504088896340736f;  // scale * log2(e)

    #define ISSUE_K(S0, BUF)                                                      \
        do { _Pragma("unroll")                                                    \
            for (int it = 0; it < 4; ++it) {                                      \
                int slab = wave * 4 + it;                                         \
                int r7   = ((slab & 1) * 4 + klr);                                \
                int g    = kph | (kpl ^ r7);                                      \
                async_cp16(k + ((size_t)(b * T_ + (S0) + slab * 4 + klr)) * H_ + g * 8, \
                           (void*)&Kl[BUF][slab * 512]);                          \
            }                                                                     \
        } while (0)

    #define ISSUE_VT(S0, BUF)                                                     \
        do { _Pragma("unroll")                                                    \
            for (int it = 0; it < 4; ++it) {                                      \
                int hbase = wave * 32 + it * 8;                                   \
                async_cp16(vt + ((size_t)(b * H_ + hbase + vrow)) * T_ + (S0) + vswz * 8, \
                           (void*)&Vtl[BUF][hbase * 64]);                         \
            }                                                                     \
        } while (0)

    ISSUE_K(0, 0);
    ISSUE_VT(0, 0);

    for (int ci = 0; ci < NC; ++ci) {
        const int buf = ci & 1;
        const int s0c = ci * BK;
        __syncthreads();   // vmcnt(0)+barrier: K(ci),V(ci) landed; buf^1 reads done
        if (ci + 1 < NC) {
            ISSUE_VT(s0c + BK, buf ^ 1);
            ISSUE_K(s0c + BK, buf ^ 1);
        }

        // St = K·Q^T, st outer / ks inner -> exp2 immediately, 8 S regs live.
        half4 pf[2][4];
        #pragma unroll
        for (int st = 0; st < 4; ++st) {
            floatx4 s0 = {0.f, 0.f, 0.f, 0.f};
            floatx4 s1 = {0.f, 0.f, 0.f, 0.f};
            #pragma unroll
            for (int ks = 0; ks < 4; ++ks) {
                int p = ((ks & 2) << 2) | ((((ks & 1) * 4) + quad) ^ c7);
                half8 kf = *(const half8*)&Kl[buf][(st * 16 + col) * 128 + p * 8];
                s0 = __builtin_amdgcn_mfma_f32_16x16x32_f16(kf, qf[0][ks], s0, 0, 0, 0);
                s1 = __builtin_amdgcn_mfma_f32_16x16x32_f16(kf, qf[1][ks], s1, 0, 0, 0);
            }
            float p0 = fexp2(s0[0] * SC), p1 = fexp2(s0[1] * SC);
            float p2 = fexp2(s0[2] * SC), p3 = fexp2(s0[3] * SC);
            lsum[0] += (p0 + p1) + (p2 + p3);
            pf[0][st] = half4{f2h(p0), f2h(p1), f2h(p2), f2h(p3)};
            p0 = fexp2(s1[0] * SC); p1 = fexp2(s1[1] * SC);
            p2 = fexp2(s1[2] * SC); p3 = fexp2(s1[3] * SC);
            lsum[1] += (p0 + p1) + (p2 + p3);
            pf[1][st] = half4{f2h(p0), f2h(p1), f2h(p2), f2h(p3)};
        }

        // PV at x32 with permuted s-order: B = lane's own P frags concatenated,
        // A = two swizzled b64 V reads (j<4 from tile 2*sp32, j>=4 from 2*sp32+1).
        #pragma unroll
        for (int sp32 = 0; sp32 < 2; ++sp32) {
            half8 p8[2];
            #pragma unroll
            for (int qt = 0; qt < 2; ++qt)
                p8[qt] = __builtin_shufflevector(pf[qt][sp32 * 2], pf[qt][sp32 * 2 + 1],
                                                 0, 1, 2, 3, 4, 5, 6, 7);
            const int pa = ((sp32 * 4 + qh) ^ c7) * 8 + ql;       // granule of tile 2*sp32
            const int pb = ((sp32 * 4 + 2 + qh) ^ c7) * 8 + ql;   // granule of tile 2*sp32+1
            #pragma unroll
            for (int ht = 0; ht < 8; ++ht) {
                const int base = ht * 1024 + col * 64;
                half4 vlo = *(const half4*)&Vtl[buf][base + pa];
                half4 vhi = *(const half4*)&Vtl[buf][base + pb];
                half8 va = __builtin_shufflevector(vlo, vhi, 0, 1, 2, 3, 4, 5, 6, 7);
                o[0][ht] = __builtin_amdgcn_mfma_f32_16x16x32_f16(va, p8[0], o[0][ht], 0, 0, 0);
                o[1][ht] = __builtin_amdgcn_mfma_f32_16x16x32_f16(va, p8[1], o[1][ht], 0, 0, 0);
            }
        }
    }
    #undef ISSUE_K
    #undef ISSUE_VT

    // epilogue: reduce lsum across quads, normalize, store final fp32
    #pragma unroll
    for (int qt = 0; qt < 2; ++qt) {
        float l = lsum[qt];
        l += __shfl_xor(l, 16);
        l += __shfl_xor(l, 32);
        float rinv = 1.0f / l;
        int qrow = q0 + wave * 32 + qt * 16 + col;
        float* orow = out + ((size_t)(b * T_ + qrow)) * H_;
        #pragma unroll
        for (int ht = 0; ht < 8; ++ht) {
            float4 st4 = {o[qt][ht][0] * rinv, o[qt][ht][1] * rinv,
                          o[qt][ht][2] * rinv, o[qt][ht][3] * rinv};
            *(float4*)&orow[ht * 16 + quad * 4] = st4;
        }
    }
}

extern "C" void kernel_launch(void* const* d_in, const int* in_sizes, int n_in,
                              void* d_out, int out_size, void* d_ws, size_t ws_size,
                              hipStream_t stream)
{
    const float* x  = (const float*)d_in[0];
    const float* Wk = (const float*)d_in[1];
    const float* Wq = (const float*)d_in[2];
    const float* Wv = (const float*)d_in[3];
    float* out = (float*)d_out;

    const size_t elems = (size_t)B_ * T_ * H_;            // 8.4M elements
    f16* qb  = (f16*)d_ws;                                // f16 q   [B][T][H]  16 MB
    f16* kb  = qb + elems;                                // f16 k   [B][T][H]  16 MB
    f16* vtb = kb + elems;                                // f16 v^T [B][H][T]  16 MB

    proj_kernel<<<dim3(B_ * 64), dim3(256), 0, stream>>>(x, Wk, Wq, Wv, qb, kb, vtb);
    attn_kernel<<<dim3(T_ / BQ, B_), dim3(256), 0, stream>>>(qb, kb, vtb, out);
}